// Round 11
// baseline (523.899 us; speedup 1.0000x reference)
//
#include <hip/hip_runtime.h>

// Problem constants
#define NB 128      // batch
#define NM 64       // sensors
#define NT 128      // snapshots
#define NG 2048     // gridpoints
#define NH 32       // hidden
// VAR_NOISE = 0.1f

// ---------------------------------------------------------------------------
// Workspace layout (floats):
//  D   [128*64*64]   off 0
//  P0  [128*64*64]   off 524288   (cov partial q0; k_invpost overwrites with S)
//  P1  [128*64*64]   off 1048576  (cov partial q1; k_invpost overwrites with M)
//  P2  [128*64*64]   off 1572864  (cov partial q2)
//  P3  [128*64*64]   off 2097152  (cov partial q3)
//  T1  [128*2048]    off 2621440
//  T2  [128*2048]    off 2883584
//  gA  [128*2048]    off 3145728
//  gB  [128*2048]    off 3407872
// R11: k_init dropped — iteration 0 passes g = nullptr; k_cov/k_mlp
// substitute 1.0f (wave-uniform pointer test, zero hot-loop cost).
// ---------------------------------------------------------------------------

// D[b] = data[b] * data[b]^T / NT    (once per call; data constant)
__global__ __launch_bounds__(256) void k_D(const float* __restrict__ data,
                                           float* __restrict__ D) {
    __shared__ float sd[64 * 133];
    int b = blockIdx.x, t = threadIdx.x;
    const float* db = data + (size_t)b * 8192;
    for (int idx = t; idx < 8192; idx += 256)
        sd[(idx >> 7) * 133 + (idx & 127)] = db[idx];
    __syncthreads();
    int i0 = (t & 15) * 4, j0 = (t >> 4) * 4;
    float acc[4][4];
#pragma unroll
    for (int r = 0; r < 4; ++r)
#pragma unroll
        for (int c = 0; c < 4; ++c) acc[r][c] = 0.f;
    for (int tt = 0; tt < 128; ++tt) {
        float av[4], bv[4];
#pragma unroll
        for (int r = 0; r < 4; ++r) av[r] = sd[(i0 + r) * 133 + tt];
#pragma unroll
        for (int c = 0; c < 4; ++c) bv[c] = sd[(j0 + c) * 133 + tt];
#pragma unroll
        for (int r = 0; r < 4; ++r)
#pragma unroll
            for (int c = 0; c < 4; ++c) acc[r][c] += av[r] * bv[c];
    }
    float* Db = D + (size_t)b * 4096;
#pragma unroll
    for (int r = 0; r < 4; ++r)
#pragma unroll
        for (int c = 0; c < 4; ++c)
            Db[(i0 + r) * 64 + j0 + c] = acc[r][c] * (1.0f / 128.0f);
}

// ---------------------------------------------------------------------------
// k_cov v2 (R8): 8x8 thread tiles, wave-split g-range, LDS tree-merge.
// R11: g == nullptr means gamma = 1 (iteration 0; replaces k_init).
// ---------------------------------------------------------------------------
__global__ __launch_bounds__(256) void k_cov(const float* __restrict__ A,
                                             const float* __restrict__ g,
                                             float* __restrict__ p0,
                                             float* __restrict__ p1,
                                             float* __restrict__ p2,
                                             float* __restrict__ p3) {
    int b = blockIdx.x >> 2, q = blockIdx.x & 3, t = threadIdx.x;
    int goff = q * 512;
    __shared__ float sA[64 * 64];    // [gg][m], one 64-g round
    __shared__ float sAg[64 * 64];   // gamma-scaled copy
    __shared__ float sg[512];
    for (int idx = t; idx < 512; idx += 256)
        sg[idx] = g ? g[(size_t)b * NG + goff + idx] : 1.0f;
    float acc[8][8];
#pragma unroll
    for (int r = 0; r < 8; ++r)
#pragma unroll
        for (int c = 0; c < 8; ++c) acc[r][c] = 0.f;
    int w = t >> 6, l = t & 63;
    int i0 = (l & 7) * 8, j0 = (l >> 3) * 8;
    int m = t >> 2, gs = (t & 3) * 16;   // staging: 4 threads/row, 16 g each

#pragma unroll 1
    for (int rd = 0; rd < 8; ++rd) {
        // issue global loads early; latency overlaps previous round's compute
        const float* Ar = A + (size_t)m * NG + goff + rd * 64 + gs;
        float4 v0 = *(const float4*)Ar;
        float4 v1 = *(const float4*)(Ar + 4);
        float4 v2 = *(const float4*)(Ar + 8);
        float4 v3 = *(const float4*)(Ar + 12);
        __syncthreads();   // previous round's sA/sAg reads complete (rd=0: sg visible)
        {
            const float* sgr = sg + rd * 64 + gs;
            float vv[16] = {v0.x, v0.y, v0.z, v0.w, v1.x, v1.y, v1.z, v1.w,
                            v2.x, v2.y, v2.z, v2.w, v3.x, v3.y, v3.z, v3.w};
#pragma unroll
            for (int u = 0; u < 16; ++u) {
                sA[(gs + u) * 64 + m] = vv[u];
                sAg[(gs + u) * 64 + m] = vv[u] * sgr[u];
            }
        }
        __syncthreads();
        // wave w accumulates its own 16-g slice of this round
#pragma unroll 4
        for (int u = 0; u < 16; ++u) {
            int gg = w * 16 + u;
            const float* avp = sAg + gg * 64 + i0;
            const float* bvp = sA + gg * 64 + j0;
            float4 a0 = *(const float4*)avp;
            float4 a1 = *(const float4*)(avp + 4);
            float4 bb0 = *(const float4*)bvp;
            float4 bb1 = *(const float4*)(bvp + 4);
            float av[8] = {a0.x, a0.y, a0.z, a0.w, a1.x, a1.y, a1.z, a1.w};
            float bv[8] = {bb0.x, bb0.y, bb0.z, bb0.w, bb1.x, bb1.y, bb1.z, bb1.w};
#pragma unroll
            for (int r = 0; r < 8; ++r)
#pragma unroll
                for (int c = 0; c < 8; ++c)
                    acc[r][c] += av[r] * bv[c];
        }
    }

    // ---- merge the 4 wave partials into wave 0 (scalar, lane-consecutive) ----
    __syncthreads();   // all compute reads of sA/sAg done; reuse as merge bufs
    if (w == 1) {
#pragma unroll
        for (int j = 0; j < 64; ++j) sA[j * 64 + l] = acc[j >> 3][j & 7];
    } else if (w == 3) {
#pragma unroll
        for (int j = 0; j < 64; ++j) sAg[j * 64 + l] = acc[j >> 3][j & 7];
    }
    __syncthreads();
    if (w == 0) {
#pragma unroll
        for (int j = 0; j < 64; ++j) acc[j >> 3][j & 7] += sA[j * 64 + l];
    } else if (w == 2) {
#pragma unroll
        for (int j = 0; j < 64; ++j) acc[j >> 3][j & 7] += sAg[j * 64 + l];
    }
    __syncthreads();
    if (w == 2) {
#pragma unroll
        for (int j = 0; j < 64; ++j) sA[j * 64 + l] = acc[j >> 3][j & 7];
    }
    __syncthreads();
    if (w == 0) {
#pragma unroll
        for (int j = 0; j < 64; ++j) acc[j >> 3][j & 7] += sA[j * 64 + l];
        float* dst = (q == 0 ? p0 : q == 1 ? p1 : q == 2 ? p2 : p3) + (size_t)b * 4096;
#pragma unroll
        for (int r = 0; r < 8; ++r) {
            *(float4*)(dst + (i0 + r) * 64 + j0) =
                make_float4(acc[r][0], acc[r][1], acc[r][2], acc[r][3]);
            *(float4*)(dst + (i0 + r) * 64 + j0 + 4) =
                make_float4(acc[r][4], acc[r][5], acc[r][6], acc[r][7]);
        }
    }
}

// ---------------------------------------------------------------------------
// k_invpost v2 (R10: -13us/dispatch): GJ column-split across ALL 4 WAVES.
// ---------------------------------------------------------------------------
#define GJSTEP_MW(RB, WB, KK)                                                 \
    {                                                                         \
        const float* krow = (RB) + (KK) * 68;                                 \
        const float* rowp = (RB) + lane * 68;                                 \
        float4 prow[4], own[4];                                               \
        _Pragma("unroll")                                                     \
        for (int bj = 0; bj < 4; ++bj) prow[bj] = *(const float4*)(krow + cb + 4 * bj); \
        _Pragma("unroll")                                                     \
        for (int bj = 0; bj < 4; ++bj) own[bj] = *(const float4*)(rowp + cb + 4 * bj);  \
        float p = krow[KK];                                                   \
        float c = rowp[KK];                                                   \
        float ps = (__builtin_fabsf(p) < 1e-12f) ? (p >= 0.f ? 1e-12f : -1e-12f) : p; \
        float pinv = __builtin_amdgcn_rcpf(ps);                               \
        bool isk = (lane == (KK));                                            \
        float n  = isk ? 0.0f : 1.0f;                                         \
        float m2 = isk ? -pinv : c * pinv;                                    \
        float* wr = (WB) + lane * 68;                                         \
        _Pragma("unroll")                                                     \
        for (int bj = 0; bj < 4; ++bj) {                                      \
            float4 res;                                                       \
            res.x = own[bj].x * n - m2 * prow[bj].x;                          \
            res.y = own[bj].y * n - m2 * prow[bj].y;                          \
            res.z = own[bj].z * n - m2 * prow[bj].z;                          \
            res.w = own[bj].w * n - m2 * prow[bj].w;                          \
            *(float4*)(wr + cb + 4 * bj) = res;                               \
        }                                                                     \
        if (((KK) >> 4) == wv)                                                \
            wr[KK] = isk ? pinv : -m2;   /* column-k fix, owning wave only */ \
    }

#define GEMMT(Ash, Bsh)                                                       \
    {                                                                         \
        _Pragma("unroll")                                                     \
        for (int rr = 0; rr < 4; ++rr)                                        \
            for (int cc = 0; cc < 4; ++cc) acc[rr][cc] = 0.f;                 \
        _Pragma("unroll 4")                                                   \
        for (int kk = 0; kk < 64; kk += 4) {                                  \
            float4 av[4], bv[4];                                              \
            _Pragma("unroll")                                                 \
            for (int qq = 0; qq < 4; ++qq) {                                  \
                av[qq] = *(const float4*)((Ash) + (kk + qq) * 68 + i0);       \
                bv[qq] = *(const float4*)((Bsh) + (kk + qq) * 68 + j0);       \
            }                                                                 \
            _Pragma("unroll")                                                 \
            for (int qq = 0; qq < 4; ++qq) {                                  \
                acc[0][0] += av[qq].x * bv[qq].x; acc[0][1] += av[qq].x * bv[qq].y; \
                acc[0][2] += av[qq].x * bv[qq].z; acc[0][3] += av[qq].x * bv[qq].w; \
                acc[1][0] += av[qq].y * bv[qq].x; acc[1][1] += av[qq].y * bv[qq].y; \
                acc[1][2] += av[qq].y * bv[qq].z; acc[1][3] += av[qq].y * bv[qq].w; \
                acc[2][0] += av[qq].z * bv[qq].x; acc[2][1] += av[qq].z * bv[qq].y; \
                acc[2][2] += av[qq].z * bv[qq].z; acc[2][3] += av[qq].z * bv[qq].w; \
                acc[3][0] += av[qq].w * bv[qq].x; acc[3][1] += av[qq].w * bv[qq].y; \
                acc[3][2] += av[qq].w * bv[qq].z; acc[3][3] += av[qq].w * bv[qq].w; \
            }                                                                 \
        }                                                                     \
    }

__global__ __launch_bounds__(256, 1) void k_invpost(const float* p0, const float* p1,
                                                    const float* p2, const float* p3,
                                                    const float* Dws,
                                                    float* Sbuf, float* Mbuf) {
    __shared__ float sX[64 * 68];   // GJ ping-pong even / final X / later D
    __shared__ float sA[64 * 68];   // Sigma copy -> X2
    __shared__ float sR[64 * 68];   // GJ ping-pong odd / R -> P
    int t = threadIdx.x, b = blockIdx.x;
    size_t boff = (size_t)b * 4096;

    // D into registers (latency hidden behind GJ phase)
    float4 dreg[4];
#pragma unroll
    for (int u = 0; u < 4; ++u)
        dreg[u] = ((const float4*)(Dws + boff))[u * 256 + t];

    // stage Sigma = p0+p1+p2+p3 + 0.1 I into sX and sA
#pragma unroll
    for (int u = 0; u < 4; ++u) {
        int idx = u * 1024 + t * 4;
        int i = idx >> 6, j = idx & 63;
        float4 v0 = *(const float4*)(p0 + boff + idx);
        float4 v1 = *(const float4*)(p1 + boff + idx);
        float4 v2 = *(const float4*)(p2 + boff + idx);
        float4 v3 = *(const float4*)(p3 + boff + idx);
        float4 v = make_float4((v0.x + v1.x) + (v2.x + v3.x),
                               (v0.y + v1.y) + (v2.y + v3.y),
                               (v0.z + v1.z) + (v2.z + v3.z),
                               (v0.w + v1.w) + (v2.w + v3.w));
        int d = i - j;
        if (d >= 0 && d < 4) (&v.x)[d] += 0.1f;
        *(float4*)(sX + i * 68 + j) = v;
        *(float4*)(sA + i * 68 + j) = v;
    }
    __syncthreads();

    // ---- Gauss-Jordan, all 4 waves (column-split), barrier per step ----
    {
        int lane = t & 63, wv = t >> 6, cb = wv * 16;
#pragma unroll 1
        for (int k2 = 0; k2 < 32; ++k2) {
            GJSTEP_MW(sX, sR, 2 * k2);        // even step: sX -> sR
            __syncthreads();
            GJSTEP_MW(sR, sX, 2 * k2 + 1);    // odd step:  sR -> sX
            __syncthreads();
        }
    }

    int i0 = (t & 15) * 4, j0 = (t >> 4) * 4;
    float acc[4][4];

    // GEMM1: R = 2I - Sigma*X   (A = sA = Sigma, symmetric -> transposed read)
    GEMMT(sA, sX);
#pragma unroll
    for (int rr = 0; rr < 4; ++rr)
#pragma unroll
        for (int cc = 0; cc < 4; ++cc)
            sR[(i0 + rr) * 68 + j0 + cc] =
                ((i0 + rr) == (j0 + cc) ? 2.0f : 0.0f) - acc[rr][cc];
    __syncthreads();

    // GEMM2: X2 = X*R  (X symmetric)  -> Sbuf global + sA (Sigma dead)
    GEMMT(sX, sR);
#pragma unroll
    for (int rr = 0; rr < 4; ++rr) {
#pragma unroll
        for (int cc = 0; cc < 4; ++cc)
            sA[(i0 + rr) * 68 + j0 + cc] = acc[rr][cc];
        *(float4*)(Sbuf + boff + (i0 + rr) * 64 + j0) =
            make_float4(acc[rr][0], acc[rr][1], acc[rr][2], acc[rr][3]);
    }
    __syncthreads();

    // scatter D into sX (X dead)
#pragma unroll
    for (int u = 0; u < 4; ++u) {
        int idx = u * 1024 + t * 4;
        *(float4*)(sX + (idx >> 6) * 68 + (idx & 63)) = dreg[u];
    }
    __syncthreads();

    // GEMM3: P = D*X2  (D symmetric) -> sR (R dead)
    GEMMT(sX, sA);
    __syncthreads();
#pragma unroll
    for (int rr = 0; rr < 4; ++rr)
#pragma unroll
        for (int cc = 0; cc < 4; ++cc)
            sR[(i0 + rr) * 68 + j0 + cc] = acc[rr][cc];
    __syncthreads();

    // GEMM4: M = X2*P  (X2 symmetric) -> Mbuf
    GEMMT(sA, sR);
#pragma unroll
    for (int rr = 0; rr < 4; ++rr)
        *(float4*)(Mbuf + boff + (i0 + rr) * 64 + j0) =
            make_float4(acc[rr][0], acc[rr][1], acc[rr][2], acc[rr][3]);
}

// ---------------------------------------------------------------------------
// k_feat v13 = v7 with 8-k phases (sa 8KB) -> LDS 40KB -> 4 blocks/CU.
// R10 analysis: v12's uniform-residency theory was never falsified — v12
// failed via VGPR 88->180 from macro-unrolled prefetch, not via 40KB/4-
// blocks itself. v13 is the clean test: v7's EXACT structure (single sa,
// barrier/load/barrier staging, no held prefetch regs), only the phase
// size halved (16k->8k, 8 phases). Grid 1024 = exactly 4 blocks/CU = one
// uniform round, no tail. Go/no-go gauge: VGPR must stay <=~100.
// Predict: LDS 40960, Occupancy 17.6->28-35%, k_feat 57.3 -> 46-51us.
// If unchanged at higher occupancy: 53% VALU is structure-intrinsic ->
// k_feat closed, target k_invpost GEMM chain next.
// ---------------------------------------------------------------------------
__global__ __launch_bounds__(256, 1) void k_feat(const float* __restrict__ A,
                                                 const float* __restrict__ Sbuf,
                                                 const float* __restrict__ Mbuf,
                                                 float* __restrict__ T1,
                                                 float* __restrict__ T2) {
    __shared__ float sS[4096];
    __shared__ float sM[4096];
    __shared__ float sa[2048];     // A-tile phase buffer: [8 k][256 g]
    int t = threadIdx.x;
    int b = blockIdx.x >> 3, tile = blockIdx.x & 7;
    const float* Abase = A + tile * 256;
    {
        const float4* S4 = (const float4*)(Sbuf + (size_t)b * 4096);
        const float4* M4 = (const float4*)(Mbuf + (size_t)b * 4096);
#pragma unroll
        for (int u = 0; u < 4; ++u) {
            ((float4*)sS)[u * 256 + t] = S4[u * 256 + t];
            ((float4*)sM)[u * 256 + t] = M4[u * 256 + t];
        }
        // stage A phase 0 (k = 0..7)
#pragma unroll
        for (int u = 0; u < 2; ++u) {
            int idx = u * 1024 + t * 4;
            int kk = idx >> 8, gl = idx & 255;
            *(float4*)(sa + idx) = *(const float4*)(Abase + (size_t)kk * NG + gl);
        }
    }
    int iq = t >> 4, gq = t & 15;
    int i0 = iq * 4;
    float accS[4][16], accM[4][16];
#pragma unroll
    for (int r = 0; r < 4; ++r)
#pragma unroll
        for (int c = 0; c < 16; ++c) { accS[r][c] = 0.f; accM[r][c] = 0.f; }
    __syncthreads();

#pragma unroll 1
    for (int p = 0; p < 8; ++p) {
        if (p) {
            __syncthreads();   // previous phase's sa reads complete
#pragma unroll
            for (int u = 0; u < 2; ++u) {
                int idx = u * 1024 + t * 4;
                int kk = idx >> 8, gl = idx & 255;
                *(float4*)(sa + idx) =
                    *(const float4*)(Abase + (size_t)(p * 8 + kk) * NG + gl);
            }
            __syncthreads();
        }
#pragma unroll 2
        for (int kk = 0; kk < 8; ++kk) {
            int k = p * 8 + kk;
            float4 sf = *(const float4*)(sS + k * 64 + i0);   // S[i0..3][k]
            float4 mf = *(const float4*)(sM + k * 64 + i0);   // M[i0..3][k]
            const float* ak = sa + kk * 256 + gq * 4;
            float4 a0 = *(const float4*)(ak);
            float4 a1 = *(const float4*)(ak + 64);
            float4 a2 = *(const float4*)(ak + 128);
            float4 a3 = *(const float4*)(ak + 192);
            float af[16] = {a0.x, a0.y, a0.z, a0.w, a1.x, a1.y, a1.z, a1.w,
                            a2.x, a2.y, a2.z, a2.w, a3.x, a3.y, a3.z, a3.w};
#pragma unroll
            for (int r = 0; r < 4; ++r) {
                float sr = (&sf.x)[r];
                float mr = (&mf.x)[r];
#pragma unroll
                for (int c = 0; c < 16; ++c) {
                    accS[r][c] += sr * af[c];
                    accM[r][c] += mr * af[c];
                }
            }
        }
    }

    // epilogue: multiply by own A rows (global, one-shot, L1-hot)
    float pS[16], pM[16];
#pragma unroll
    for (int c = 0; c < 16; ++c) { pS[c] = 0.f; pM[c] = 0.f; }
#pragma unroll
    for (int r = 0; r < 4; ++r) {
        const float* arp = A + (size_t)(i0 + r) * NG + tile * 256 + gq * 4;
        float4 b0 = *(const float4*)(arp);
        float4 b1 = *(const float4*)(arp + 64);
        float4 b2 = *(const float4*)(arp + 128);
        float4 b3 = *(const float4*)(arp + 192);
        float ar[16] = {b0.x, b0.y, b0.z, b0.w, b1.x, b1.y, b1.z, b1.w,
                        b2.x, b2.y, b2.z, b2.w, b3.x, b3.y, b3.z, b3.w};
#pragma unroll
        for (int c = 0; c < 16; ++c) {
            pS[c] += ar[c] * accS[r][c];
            pM[c] += ar[c] * accM[r][c];
        }
    }
    __syncthreads();   // k-loop reads of sS/sM done; reuse as scratch

    // scratch: sS[iq][g_local] S-partials, sM likewise (16 x 256)
#pragma unroll
    for (int ch = 0; ch < 4; ++ch) {
        *(float4*)(sS + iq * 256 + ch * 64 + gq * 4) =
            make_float4(pS[ch * 4], pS[ch * 4 + 1], pS[ch * 4 + 2], pS[ch * 4 + 3]);
        *(float4*)(sM + iq * 256 + ch * 64 + gq * 4) =
            make_float4(pM[ch * 4], pM[ch * 4 + 1], pM[ch * 4 + 2], pM[ch * 4 + 3]);
    }
    __syncthreads();

    // final 16-way reduce: thread t owns g_local = t (lanes consecutive: no conflict)
    float sumS = 0.f, sumM = 0.f;
#pragma unroll
    for (int q = 0; q < 16; ++q) {
        sumS += sS[q * 256 + t];
        sumM += sM[q * 256 + t];
    }
    size_t base = (size_t)b * NG + tile * 256 + t;
    T2[base] = fabsf(sumS);
    T1[base] = sumM;
}

// ---------------------------------------------------------------------------
// k_mlp v3 (R7). R11: gcur == nullptr means gamma = 1 (iteration 0).
// ---------------------------------------------------------------------------
__global__ __launch_bounds__(256, 1) void k_mlp(const float* __restrict__ T1,
                                                const float* __restrict__ T2,
                                                const float* __restrict__ gcur,
                                                const float* __restrict__ W1,
                                                const float* __restrict__ b1,
                                                const float* __restrict__ W2,
                                                const float* __restrict__ b2,
                                                const float* __restrict__ W3,
                                                const float* __restrict__ b3,
                                                int it, float* __restrict__ out) {
    // LDS regions (floats): W1 [0,800) stride 100 | b1 [800,1088) stride 36
    // | W2 [1088,9312) stride 1028 | b2 [9312,9600) stride 36
    // | W3 [9600,9888) stride 36 | b3 [9888,9896)
    __shared__ float w[9896];
    int t = threadIdx.x, g0 = blockIdx.x * 8;
    {
        size_t gbase = (size_t)it * NG + g0;
        const float* srcW1 = W1 + gbase * 96;
        const float* srcB1 = b1 + gbase * 32;
        const float* srcW2 = W2 + gbase * 1024;
        const float* srcB2 = b2 + gbase * 32;
        const float* srcW3 = W3 + gbase * 32;
        const float* srcB3 = b3 + gbase;
#pragma unroll
        for (int u = 0; u < 8; ++u)   // W2: one gl per u (2048 f4 / 8)
            *(float4*)(w + 1088 + u * 1028 + t * 4) =
                ((const float4*)srcW2)[u * 256 + t];
        if (t < 192) {                // W1: 192 f4 = 8 gl x 24 f4
            int gl = t / 24, j4 = t % 24;
            *(float4*)(w + gl * 100 + j4 * 4) = ((const float4*)srcW1)[t];
        } else {                      // b1: 64 f4 = 8 gl x 8 f4
            int i = t - 192, gl = i >> 3, j4 = i & 7;
            *(float4*)(w + 800 + gl * 36 + j4 * 4) = ((const float4*)srcB1)[i];
        }
        if (t < 64) {                 // b2
            int gl = t >> 3, j4 = t & 7;
            *(float4*)(w + 9312 + gl * 36 + j4 * 4) = ((const float4*)srcB2)[t];
        } else if (t < 128) {         // W3
            int i = t - 64, gl = i >> 3, j4 = i & 7;
            *(float4*)(w + 9600 + gl * 36 + j4 * 4) = ((const float4*)srcW3)[i];
        } else if (t < 136) {         // b3: 8 scalars
            w[9888 + (t - 128)] = srcB3[t - 128];
        }
    }
    __syncthreads();
    int gl = t & 7, gg = g0 + gl;
    const float* w1d = w + gl * 100;
    const float* b1d = w + 800 + gl * 36;
    const float* w2d = w + 1088 + gl * 1028;
    const float* b2d = w + 9312 + gl * 36;
    const float* w3d = w + 9600 + gl * 36;
    float b3v = w[9888 + gl];
    int b0 = t >> 3;                 // 0..31; batch points b0 + {0,32,64,96}

    float x0[4], x1[4], x2[4];
#pragma unroll
    for (int c = 0; c < 4; ++c) {
        size_t xo = (size_t)(b0 + c * 32) * NG + gg;
        x0[c] = T1[xo]; x1[c] = T2[xo];
        x2[c] = gcur ? gcur[xo] : 1.0f;
    }

    float h1[4][32];
#pragma unroll
    for (int k = 0; k < 32; k += 4) {
        float4 wa = *(const float4*)(w1d + k);
        float4 wb = *(const float4*)(w1d + 32 + k);
        float4 wc = *(const float4*)(w1d + 64 + k);
        float4 bv = *(const float4*)(b1d + k);
#pragma unroll
        for (int c = 0; c < 4; ++c) {
            h1[c][k + 0] = fmaxf(0.f, x0[c] * wa.x + x1[c] * wb.x + x2[c] * wc.x + bv.x);
            h1[c][k + 1] = fmaxf(0.f, x0[c] * wa.y + x1[c] * wb.y + x2[c] * wc.y + bv.y);
            h1[c][k + 2] = fmaxf(0.f, x0[c] * wa.z + x1[c] * wb.z + x2[c] * wc.z + bv.z);
            h1[c][k + 3] = fmaxf(0.f, x0[c] * wa.w + x1[c] * wb.w + x2[c] * wc.w + bv.w);
        }
    }

    float acc[4];
#pragma unroll
    for (int c = 0; c < 4; ++c) acc[c] = b3v;
#pragma unroll 1
    for (int k = 0; k < 32; k += 4) {
        float4 hb = *(const float4*)(b2d + k);
        float v[4][4];
#pragma unroll
        for (int c = 0; c < 4; ++c) {
            v[c][0] = hb.x; v[c][1] = hb.y; v[c][2] = hb.z; v[c][3] = hb.w;
        }
#pragma unroll
        for (int j = 0; j < 32; ++j) {
            float4 w2v = *(const float4*)(w2d + j * 32 + k);
#pragma unroll
            for (int c = 0; c < 4; ++c) {
                v[c][0] += h1[c][j] * w2v.x;
                v[c][1] += h1[c][j] * w2v.y;
                v[c][2] += h1[c][j] * w2v.z;
                v[c][3] += h1[c][j] * w2v.w;
            }
        }
        float4 w3v = *(const float4*)(w3d + k);
#pragma unroll
        for (int c = 0; c < 4; ++c) {
            acc[c] += fmaxf(0.f, v[c][0]) * w3v.x + fmaxf(0.f, v[c][1]) * w3v.y +
                      fmaxf(0.f, v[c][2]) * w3v.z + fmaxf(0.f, v[c][3]) * w3v.w;
        }
    }
#pragma unroll
    for (int c = 0; c < 4; ++c)
        out[(size_t)(b0 + c * 32) * NG + gg] = acc[c];
}

extern "C" void kernel_launch(void* const* d_in, const int* in_sizes, int n_in,
                              void* d_out, int out_size, void* d_ws, size_t ws_size,
                              hipStream_t stream) {
    const float* data = (const float*)d_in[0];
    const float* A    = (const float*)d_in[1];
    const float* W1   = (const float*)d_in[2];
    const float* b1   = (const float*)d_in[3];
    const float* W2   = (const float*)d_in[4];
    const float* b2   = (const float*)d_in[5];
    const float* W3   = (const float*)d_in[6];
    const float* b3   = (const float*)d_in[7];
    float* out = (float*)d_out;
    float* ws = (float*)d_ws;

    float* D  = ws;
    float* P0 = ws + 524288;    // becomes S
    float* P1 = ws + 1048576;   // becomes M
    float* P2 = ws + 1572864;
    float* P3 = ws + 2097152;
    float* T1 = ws + 2621440;
    float* T2 = ws + 2883584;
    float* gA = ws + 3145728;
    float* gB = ws + 3407872;

    k_D<<<dim3(128), dim3(256), 0, stream>>>(data, D);

    float* gc = gA;
    float* gn = gB;
    for (int it = 0; it < 3; ++it) {
        const float* gin = (it == 0) ? nullptr : gc;
        k_cov<<<dim3(512), dim3(256), 0, stream>>>(A, gin, P0, P1, P2, P3);
        k_invpost<<<dim3(128), dim3(256), 0, stream>>>(P0, P1, P2, P3, D, P0, P1);
        k_feat<<<dim3(1024), dim3(256), 0, stream>>>(A, P0, P1, T1, T2);
        float* dst = (it == 2) ? out : gn;
        k_mlp<<<dim3(256), dim3(256), 0, stream>>>(T1, T2, gin, W1, b1, W2, b2, W3, b3, it, dst);
        float* tmp = gc; gc = gn; gn = tmp;
    }
}

// Round 12
// 502.104 us; speedup vs baseline: 1.0434x; 1.0434x over previous
//
#include <hip/hip_runtime.h>

// Problem constants
#define NB 128      // batch
#define NM 64       // sensors
#define NT 128      // snapshots
#define NG 2048     // gridpoints
#define NH 32       // hidden
// VAR_NOISE = 0.1f

// ---------------------------------------------------------------------------
// Workspace layout (floats):
//  D   [128*64*64]   off 0
//  P0  [128*64*64]   off 524288   (cov partial q0; k_invpost overwrites with S)
//  P1  [128*64*64]   off 1048576  (cov partial q1; k_invpost overwrites with M)
//  P2  [128*64*64]   off 1572864  (cov partial q2)
//  P3  [128*64*64]   off 2097152  (cov partial q3)
//  T1  [128*2048]    off 2621440
//  T2  [128*2048]    off 2883584
//  gA  [128*2048]    off 3145728
//  gB  [128*2048]    off 3407872
// R11: k_init dropped — iteration 0 passes g = nullptr (1.0f substituted).
// ---------------------------------------------------------------------------

// D[b] = data[b] * data[b]^T / NT    (once per call; data constant)
__global__ __launch_bounds__(256) void k_D(const float* __restrict__ data,
                                           float* __restrict__ D) {
    __shared__ float sd[64 * 133];
    int b = blockIdx.x, t = threadIdx.x;
    const float* db = data + (size_t)b * 8192;
    for (int idx = t; idx < 8192; idx += 256)
        sd[(idx >> 7) * 133 + (idx & 127)] = db[idx];
    __syncthreads();
    int i0 = (t & 15) * 4, j0 = (t >> 4) * 4;
    float acc[4][4];
#pragma unroll
    for (int r = 0; r < 4; ++r)
#pragma unroll
        for (int c = 0; c < 4; ++c) acc[r][c] = 0.f;
    for (int tt = 0; tt < 128; ++tt) {
        float av[4], bv[4];
#pragma unroll
        for (int r = 0; r < 4; ++r) av[r] = sd[(i0 + r) * 133 + tt];
#pragma unroll
        for (int c = 0; c < 4; ++c) bv[c] = sd[(j0 + c) * 133 + tt];
#pragma unroll
        for (int r = 0; r < 4; ++r)
#pragma unroll
            for (int c = 0; c < 4; ++c) acc[r][c] += av[r] * bv[c];
    }
    float* Db = D + (size_t)b * 4096;
#pragma unroll
    for (int r = 0; r < 4; ++r)
#pragma unroll
        for (int c = 0; c < 4; ++c)
            Db[(i0 + r) * 64 + j0 + c] = acc[r][c] * (1.0f / 128.0f);
}

// ---------------------------------------------------------------------------
// k_cov v2 (R8): 8x8 thread tiles, wave-split g-range, LDS tree-merge.
// g == nullptr means gamma = 1 (iteration 0; replaces k_init).
// ---------------------------------------------------------------------------
__global__ __launch_bounds__(256) void k_cov(const float* __restrict__ A,
                                             const float* __restrict__ g,
                                             float* __restrict__ p0,
                                             float* __restrict__ p1,
                                             float* __restrict__ p2,
                                             float* __restrict__ p3) {
    int b = blockIdx.x >> 2, q = blockIdx.x & 3, t = threadIdx.x;
    int goff = q * 512;
    __shared__ float sA[64 * 64];    // [gg][m], one 64-g round
    __shared__ float sAg[64 * 64];   // gamma-scaled copy
    __shared__ float sg[512];
    for (int idx = t; idx < 512; idx += 256)
        sg[idx] = g ? g[(size_t)b * NG + goff + idx] : 1.0f;
    float acc[8][8];
#pragma unroll
    for (int r = 0; r < 8; ++r)
#pragma unroll
        for (int c = 0; c < 8; ++c) acc[r][c] = 0.f;
    int w = t >> 6, l = t & 63;
    int i0 = (l & 7) * 8, j0 = (l >> 3) * 8;
    int m = t >> 2, gs = (t & 3) * 16;   // staging: 4 threads/row, 16 g each

#pragma unroll 1
    for (int rd = 0; rd < 8; ++rd) {
        // issue global loads early; latency overlaps previous round's compute
        const float* Ar = A + (size_t)m * NG + goff + rd * 64 + gs;
        float4 v0 = *(const float4*)Ar;
        float4 v1 = *(const float4*)(Ar + 4);
        float4 v2 = *(const float4*)(Ar + 8);
        float4 v3 = *(const float4*)(Ar + 12);
        __syncthreads();   // previous round's sA/sAg reads complete (rd=0: sg visible)
        {
            const float* sgr = sg + rd * 64 + gs;
            float vv[16] = {v0.x, v0.y, v0.z, v0.w, v1.x, v1.y, v1.z, v1.w,
                            v2.x, v2.y, v2.z, v2.w, v3.x, v3.y, v3.z, v3.w};
#pragma unroll
            for (int u = 0; u < 16; ++u) {
                sA[(gs + u) * 64 + m] = vv[u];
                sAg[(gs + u) * 64 + m] = vv[u] * sgr[u];
            }
        }
        __syncthreads();
        // wave w accumulates its own 16-g slice of this round
#pragma unroll 4
        for (int u = 0; u < 16; ++u) {
            int gg = w * 16 + u;
            const float* avp = sAg + gg * 64 + i0;
            const float* bvp = sA + gg * 64 + j0;
            float4 a0 = *(const float4*)avp;
            float4 a1 = *(const float4*)(avp + 4);
            float4 bb0 = *(const float4*)bvp;
            float4 bb1 = *(const float4*)(bvp + 4);
            float av[8] = {a0.x, a0.y, a0.z, a0.w, a1.x, a1.y, a1.z, a1.w};
            float bv[8] = {bb0.x, bb0.y, bb0.z, bb0.w, bb1.x, bb1.y, bb1.z, bb1.w};
#pragma unroll
            for (int r = 0; r < 8; ++r)
#pragma unroll
                for (int c = 0; c < 8; ++c)
                    acc[r][c] += av[r] * bv[c];
        }
    }

    // ---- merge the 4 wave partials into wave 0 (scalar, lane-consecutive) ----
    __syncthreads();   // all compute reads of sA/sAg done; reuse as merge bufs
    if (w == 1) {
#pragma unroll
        for (int j = 0; j < 64; ++j) sA[j * 64 + l] = acc[j >> 3][j & 7];
    } else if (w == 3) {
#pragma unroll
        for (int j = 0; j < 64; ++j) sAg[j * 64 + l] = acc[j >> 3][j & 7];
    }
    __syncthreads();
    if (w == 0) {
#pragma unroll
        for (int j = 0; j < 64; ++j) acc[j >> 3][j & 7] += sA[j * 64 + l];
    } else if (w == 2) {
#pragma unroll
        for (int j = 0; j < 64; ++j) acc[j >> 3][j & 7] += sAg[j * 64 + l];
    }
    __syncthreads();
    if (w == 2) {
#pragma unroll
        for (int j = 0; j < 64; ++j) sA[j * 64 + l] = acc[j >> 3][j & 7];
    }
    __syncthreads();
    if (w == 0) {
#pragma unroll
        for (int j = 0; j < 64; ++j) acc[j >> 3][j & 7] += sA[j * 64 + l];
        float* dst = (q == 0 ? p0 : q == 1 ? p1 : q == 2 ? p2 : p3) + (size_t)b * 4096;
#pragma unroll
        for (int r = 0; r < 8; ++r) {
            *(float4*)(dst + (i0 + r) * 64 + j0) =
                make_float4(acc[r][0], acc[r][1], acc[r][2], acc[r][3]);
            *(float4*)(dst + (i0 + r) * 64 + j0 + 4) =
                make_float4(acc[r][4], acc[r][5], acc[r][6], acc[r][7]);
        }
    }
}

// ---------------------------------------------------------------------------
// k_invpost v2 (R10: -13us/dispatch): GJ column-split across ALL 4 WAVES.
// ---------------------------------------------------------------------------
#define GJSTEP_MW(RB, WB, KK)                                                 \
    {                                                                         \
        const float* krow = (RB) + (KK) * 68;                                 \
        const float* rowp = (RB) + lane * 68;                                 \
        float4 prow[4], own[4];                                               \
        _Pragma("unroll")                                                     \
        for (int bj = 0; bj < 4; ++bj) prow[bj] = *(const float4*)(krow + cb + 4 * bj); \
        _Pragma("unroll")                                                     \
        for (int bj = 0; bj < 4; ++bj) own[bj] = *(const float4*)(rowp + cb + 4 * bj);  \
        float p = krow[KK];                                                   \
        float c = rowp[KK];                                                   \
        float ps = (__builtin_fabsf(p) < 1e-12f) ? (p >= 0.f ? 1e-12f : -1e-12f) : p; \
        float pinv = __builtin_amdgcn_rcpf(ps);                               \
        bool isk = (lane == (KK));                                            \
        float n  = isk ? 0.0f : 1.0f;                                         \
        float m2 = isk ? -pinv : c * pinv;                                    \
        float* wr = (WB) + lane * 68;                                         \
        _Pragma("unroll")                                                     \
        for (int bj = 0; bj < 4; ++bj) {                                      \
            float4 res;                                                       \
            res.x = own[bj].x * n - m2 * prow[bj].x;                          \
            res.y = own[bj].y * n - m2 * prow[bj].y;                          \
            res.z = own[bj].z * n - m2 * prow[bj].z;                          \
            res.w = own[bj].w * n - m2 * prow[bj].w;                          \
            *(float4*)(wr + cb + 4 * bj) = res;                               \
        }                                                                     \
        if (((KK) >> 4) == wv)                                                \
            wr[KK] = isk ? pinv : -m2;   /* column-k fix, owning wave only */ \
    }

#define GEMMT(Ash, Bsh)                                                       \
    {                                                                         \
        _Pragma("unroll")                                                     \
        for (int rr = 0; rr < 4; ++rr)                                        \
            for (int cc = 0; cc < 4; ++cc) acc[rr][cc] = 0.f;                 \
        _Pragma("unroll 4")                                                   \
        for (int kk = 0; kk < 64; kk += 4) {                                  \
            float4 av[4], bv[4];                                              \
            _Pragma("unroll")                                                 \
            for (int qq = 0; qq < 4; ++qq) {                                  \
                av[qq] = *(const float4*)((Ash) + (kk + qq) * 68 + i0);       \
                bv[qq] = *(const float4*)((Bsh) + (kk + qq) * 68 + j0);       \
            }                                                                 \
            _Pragma("unroll")                                                 \
            for (int qq = 0; qq < 4; ++qq) {                                  \
                acc[0][0] += av[qq].x * bv[qq].x; acc[0][1] += av[qq].x * bv[qq].y; \
                acc[0][2] += av[qq].x * bv[qq].z; acc[0][3] += av[qq].x * bv[qq].w; \
                acc[1][0] += av[qq].y * bv[qq].x; acc[1][1] += av[qq].y * bv[qq].y; \
                acc[1][2] += av[qq].y * bv[qq].z; acc[1][3] += av[qq].y * bv[qq].w; \
                acc[2][0] += av[qq].z * bv[qq].x; acc[2][1] += av[qq].z * bv[qq].y; \
                acc[2][2] += av[qq].z * bv[qq].z; acc[2][3] += av[qq].z * bv[qq].w; \
                acc[3][0] += av[qq].w * bv[qq].x; acc[3][1] += av[qq].w * bv[qq].y; \
                acc[3][2] += av[qq].w * bv[qq].z; acc[3][3] += av[qq].w * bv[qq].w; \
            }                                                                 \
        }                                                                     \
    }

__global__ __launch_bounds__(256, 1) void k_invpost(const float* p0, const float* p1,
                                                    const float* p2, const float* p3,
                                                    const float* Dws,
                                                    float* Sbuf, float* Mbuf) {
    __shared__ float sX[64 * 68];   // GJ ping-pong even / final X / later D
    __shared__ float sA[64 * 68];   // Sigma copy -> X2
    __shared__ float sR[64 * 68];   // GJ ping-pong odd / R -> P
    int t = threadIdx.x, b = blockIdx.x;
    size_t boff = (size_t)b * 4096;

    // D into registers (latency hidden behind GJ phase)
    float4 dreg[4];
#pragma unroll
    for (int u = 0; u < 4; ++u)
        dreg[u] = ((const float4*)(Dws + boff))[u * 256 + t];

    // stage Sigma = p0+p1+p2+p3 + 0.1 I into sX and sA
#pragma unroll
    for (int u = 0; u < 4; ++u) {
        int idx = u * 1024 + t * 4;
        int i = idx >> 6, j = idx & 63;
        float4 v0 = *(const float4*)(p0 + boff + idx);
        float4 v1 = *(const float4*)(p1 + boff + idx);
        float4 v2 = *(const float4*)(p2 + boff + idx);
        float4 v3 = *(const float4*)(p3 + boff + idx);
        float4 v = make_float4((v0.x + v1.x) + (v2.x + v3.x),
                               (v0.y + v1.y) + (v2.y + v3.y),
                               (v0.z + v1.z) + (v2.z + v3.z),
                               (v0.w + v1.w) + (v2.w + v3.w));
        int d = i - j;
        if (d >= 0 && d < 4) (&v.x)[d] += 0.1f;
        *(float4*)(sX + i * 68 + j) = v;
        *(float4*)(sA + i * 68 + j) = v;
    }
    __syncthreads();

    // ---- Gauss-Jordan, all 4 waves (column-split), barrier per step ----
    {
        int lane = t & 63, wv = t >> 6, cb = wv * 16;
#pragma unroll 1
        for (int k2 = 0; k2 < 32; ++k2) {
            GJSTEP_MW(sX, sR, 2 * k2);        // even step: sX -> sR
            __syncthreads();
            GJSTEP_MW(sR, sX, 2 * k2 + 1);    // odd step:  sR -> sX
            __syncthreads();
        }
    }

    int i0 = (t & 15) * 4, j0 = (t >> 4) * 4;
    float acc[4][4];

    // GEMM1: R = 2I - Sigma*X   (A = sA = Sigma, symmetric -> transposed read)
    GEMMT(sA, sX);
#pragma unroll
    for (int rr = 0; rr < 4; ++rr)
#pragma unroll
        for (int cc = 0; cc < 4; ++cc)
            sR[(i0 + rr) * 68 + j0 + cc] =
                ((i0 + rr) == (j0 + cc) ? 2.0f : 0.0f) - acc[rr][cc];
    __syncthreads();

    // GEMM2: X2 = X*R  (X symmetric)  -> Sbuf global + sA (Sigma dead)
    GEMMT(sX, sR);
#pragma unroll
    for (int rr = 0; rr < 4; ++rr) {
#pragma unroll
        for (int cc = 0; cc < 4; ++cc)
            sA[(i0 + rr) * 68 + j0 + cc] = acc[rr][cc];
        *(float4*)(Sbuf + boff + (i0 + rr) * 64 + j0) =
            make_float4(acc[rr][0], acc[rr][1], acc[rr][2], acc[rr][3]);
    }
    __syncthreads();

    // scatter D into sX (X dead)
#pragma unroll
    for (int u = 0; u < 4; ++u) {
        int idx = u * 1024 + t * 4;
        *(float4*)(sX + (idx >> 6) * 68 + (idx & 63)) = dreg[u];
    }
    __syncthreads();

    // GEMM3: P = D*X2  (D symmetric) -> sR (R dead)
    GEMMT(sX, sA);
    __syncthreads();
#pragma unroll
    for (int rr = 0; rr < 4; ++rr)
#pragma unroll
        for (int cc = 0; cc < 4; ++cc)
            sR[(i0 + rr) * 68 + j0 + cc] = acc[rr][cc];
    __syncthreads();

    // GEMM4: M = X2*P  (X2 symmetric) -> Mbuf
    GEMMT(sA, sR);
#pragma unroll
    for (int rr = 0; rr < 4; ++rr)
        *(float4*)(Mbuf + boff + (i0 + rr) * 64 + j0) =
            make_float4(acc[rr][0], acc[rr][1], acc[rr][2], acc[rr][3]);
}

// ---------------------------------------------------------------------------
// k_feat v7 RESTORED (proven 57.2-58.4us). R11 closed this kernel: v13's
// clean residency test (40KB, VGPR 88 held) did NOT raise occupancy —
// the ~200-unified-reg footprint (128 accums invisible in arch count)
// caps 2 waves/SIMD regardless of LDS; extra barriers cost +4.6us.
// v7's 53% VALUBusy is structure-intrinsic. Do not touch again.
// ---------------------------------------------------------------------------
__global__ __launch_bounds__(256, 1) void k_feat(const float* __restrict__ A,
                                                 const float* __restrict__ Sbuf,
                                                 const float* __restrict__ Mbuf,
                                                 float* __restrict__ T1,
                                                 float* __restrict__ T2) {
    __shared__ float sS[4096];
    __shared__ float sM[4096];
    __shared__ float sa[4096];     // A-tile phase buffer: [16 k][256 g]
    int t = threadIdx.x;
    int b = blockIdx.x >> 3, tile = blockIdx.x & 7;
    const float* Abase = A + tile * 256;
    {
        const float4* S4 = (const float4*)(Sbuf + (size_t)b * 4096);
        const float4* M4 = (const float4*)(Mbuf + (size_t)b * 4096);
#pragma unroll
        for (int u = 0; u < 4; ++u) {
            ((float4*)sS)[u * 256 + t] = S4[u * 256 + t];
            ((float4*)sM)[u * 256 + t] = M4[u * 256 + t];
        }
        // stage A phase 0 (k = 0..15)
#pragma unroll
        for (int u = 0; u < 4; ++u) {
            int idx = u * 1024 + t * 4;
            int kk = idx >> 8, gl = idx & 255;
            *(float4*)(sa + idx) = *(const float4*)(Abase + (size_t)kk * NG + gl);
        }
    }
    int iq = t >> 4, gq = t & 15;
    int i0 = iq * 4;
    float accS[4][16], accM[4][16];
#pragma unroll
    for (int r = 0; r < 4; ++r)
#pragma unroll
        for (int c = 0; c < 16; ++c) { accS[r][c] = 0.f; accM[r][c] = 0.f; }
    __syncthreads();

#pragma unroll 1
    for (int p = 0; p < 4; ++p) {
        if (p) {
            __syncthreads();   // previous phase's sa reads complete
#pragma unroll
            for (int u = 0; u < 4; ++u) {
                int idx = u * 1024 + t * 4;
                int kk = idx >> 8, gl = idx & 255;
                *(float4*)(sa + idx) =
                    *(const float4*)(Abase + (size_t)(p * 16 + kk) * NG + gl);
            }
            __syncthreads();
        }
#pragma unroll 2
        for (int kk = 0; kk < 16; ++kk) {
            int k = p * 16 + kk;
            float4 sf = *(const float4*)(sS + k * 64 + i0);   // S[i0..3][k]
            float4 mf = *(const float4*)(sM + k * 64 + i0);   // M[i0..3][k]
            const float* ak = sa + kk * 256 + gq * 4;
            float4 a0 = *(const float4*)(ak);
            float4 a1 = *(const float4*)(ak + 64);
            float4 a2 = *(const float4*)(ak + 128);
            float4 a3 = *(const float4*)(ak + 192);
            float af[16] = {a0.x, a0.y, a0.z, a0.w, a1.x, a1.y, a1.z, a1.w,
                            a2.x, a2.y, a2.z, a2.w, a3.x, a3.y, a3.z, a3.w};
#pragma unroll
            for (int r = 0; r < 4; ++r) {
                float sr = (&sf.x)[r];
                float mr = (&mf.x)[r];
#pragma unroll
                for (int c = 0; c < 16; ++c) {
                    accS[r][c] += sr * af[c];
                    accM[r][c] += mr * af[c];
                }
            }
        }
    }

    // epilogue: multiply by own A rows (global, one-shot, L1-hot)
    float pS[16], pM[16];
#pragma unroll
    for (int c = 0; c < 16; ++c) { pS[c] = 0.f; pM[c] = 0.f; }
#pragma unroll
    for (int r = 0; r < 4; ++r) {
        const float* arp = A + (size_t)(i0 + r) * NG + tile * 256 + gq * 4;
        float4 b0 = *(const float4*)(arp);
        float4 b1 = *(const float4*)(arp + 64);
        float4 b2 = *(const float4*)(arp + 128);
        float4 b3 = *(const float4*)(arp + 192);
        float ar[16] = {b0.x, b0.y, b0.z, b0.w, b1.x, b1.y, b1.z, b1.w,
                        b2.x, b2.y, b2.z, b2.w, b3.x, b3.y, b3.z, b3.w};
#pragma unroll
        for (int c = 0; c < 16; ++c) {
            pS[c] += ar[c] * accS[r][c];
            pM[c] += ar[c] * accM[r][c];
        }
    }
    __syncthreads();   // k-loop reads of sS/sM done; reuse as scratch

    // scratch: sS[iq][g_local] S-partials, sM likewise (16 x 256)
#pragma unroll
    for (int ch = 0; ch < 4; ++ch) {
        *(float4*)(sS + iq * 256 + ch * 64 + gq * 4) =
            make_float4(pS[ch * 4], pS[ch * 4 + 1], pS[ch * 4 + 2], pS[ch * 4 + 3]);
        *(float4*)(sM + iq * 256 + ch * 64 + gq * 4) =
            make_float4(pM[ch * 4], pM[ch * 4 + 1], pM[ch * 4 + 2], pM[ch * 4 + 3]);
    }
    __syncthreads();

    // final 16-way reduce: thread t owns g_local = t (lanes consecutive: no conflict)
    float sumS = 0.f, sumM = 0.f;
#pragma unroll
    for (int q = 0; q < 16; ++q) {
        sumS += sS[q * 256 + t];
        sumM += sM[q * 256 + t];
    }
    size_t base = (size_t)b * NG + tile * 256 + t;
    T2[base] = fabsf(sumS);
    T1[base] = sumM;
}

// ---------------------------------------------------------------------------
// k_mlp v4: batch-split for TLP. R11 theory: v3 at grid 256 = 1 block/CU
// = 1 WAVE/SIMD — zero latency hiding; measured ~47us vs VALU floor 3.9us
// + LDS floor 1.7us. v4: grid 512, bid&1 selects batch half (64 points,
// 2/thread via c*32); same 8-gl weight staging per block (both halves
// stage identical weights — consecutive blocks L2-hit). h1[2][32] halves
// regs; W2 amortization 4x->2x raises LDS floor to 3.4us, still under
// VALU 3.9us. 2 blocks/CU -> 2 waves/SIMD: one wave's ds_read latency
// hides under the other's FMAs. Predict 47 -> ~12-20us/dispatch.
// gcur == nullptr means gamma = 1 (iteration 0).
// ---------------------------------------------------------------------------
__global__ __launch_bounds__(256, 1) void k_mlp(const float* __restrict__ T1,
                                                const float* __restrict__ T2,
                                                const float* __restrict__ gcur,
                                                const float* __restrict__ W1,
                                                const float* __restrict__ b1,
                                                const float* __restrict__ W2,
                                                const float* __restrict__ b2,
                                                const float* __restrict__ W3,
                                                const float* __restrict__ b3,
                                                int it, float* __restrict__ out) {
    // LDS regions (floats): W1 [0,800) stride 100 | b1 [800,1088) stride 36
    // | W2 [1088,9312) stride 1028 | b2 [9312,9600) stride 36
    // | W3 [9600,9888) stride 36 | b3 [9888,9896)
    __shared__ float w[9896];
    int t = threadIdx.x;
    int gb = blockIdx.x >> 1, half = blockIdx.x & 1;
    int g0 = gb * 8;
    {
        size_t gbase = (size_t)it * NG + g0;
        const float* srcW1 = W1 + gbase * 96;
        const float* srcB1 = b1 + gbase * 32;
        const float* srcW2 = W2 + gbase * 1024;
        const float* srcB2 = b2 + gbase * 32;
        const float* srcW3 = W3 + gbase * 32;
        const float* srcB3 = b3 + gbase;
#pragma unroll
        for (int u = 0; u < 8; ++u)   // W2: one gl per u (2048 f4 / 8)
            *(float4*)(w + 1088 + u * 1028 + t * 4) =
                ((const float4*)srcW2)[u * 256 + t];
        if (t < 192) {                // W1: 192 f4 = 8 gl x 24 f4
            int gl = t / 24, j4 = t % 24;
            *(float4*)(w + gl * 100 + j4 * 4) = ((const float4*)srcW1)[t];
        } else {                      // b1: 64 f4 = 8 gl x 8 f4
            int i = t - 192, gl = i >> 3, j4 = i & 7;
            *(float4*)(w + 800 + gl * 36 + j4 * 4) = ((const float4*)srcB1)[i];
        }
        if (t < 64) {                 // b2
            int gl = t >> 3, j4 = t & 7;
            *(float4*)(w + 9312 + gl * 36 + j4 * 4) = ((const float4*)srcB2)[t];
        } else if (t < 128) {         // W3
            int i = t - 64, gl = i >> 3, j4 = i & 7;
            *(float4*)(w + 9600 + gl * 36 + j4 * 4) = ((const float4*)srcW3)[i];
        } else if (t < 136) {         // b3: 8 scalars
            w[9888 + (t - 128)] = srcB3[t - 128];
        }
    }
    __syncthreads();
    int gl = t & 7, gg = g0 + gl;
    const float* w1d = w + gl * 100;
    const float* b1d = w + 800 + gl * 36;
    const float* w2d = w + 1088 + gl * 1028;
    const float* b2d = w + 9312 + gl * 36;
    const float* w3d = w + 9600 + gl * 36;
    float b3v = w[9888 + gl];
    int b0 = (t >> 3) + half * 64;   // batch base; c*32 adds {0,32}

    float x0[2], x1[2], x2[2];
#pragma unroll
    for (int c = 0; c < 2; ++c) {
        size_t xo = (size_t)(b0 + c * 32) * NG + gg;
        x0[c] = T1[xo]; x1[c] = T2[xo];
        x2[c] = gcur ? gcur[xo] : 1.0f;
    }

    float h1[2][32];
#pragma unroll
    for (int k = 0; k < 32; k += 4) {
        float4 wa = *(const float4*)(w1d + k);
        float4 wb = *(const float4*)(w1d + 32 + k);
        float4 wc = *(const float4*)(w1d + 64 + k);
        float4 bv = *(const float4*)(b1d + k);
#pragma unroll
        for (int c = 0; c < 2; ++c) {
            h1[c][k + 0] = fmaxf(0.f, x0[c] * wa.x + x1[c] * wb.x + x2[c] * wc.x + bv.x);
            h1[c][k + 1] = fmaxf(0.f, x0[c] * wa.y + x1[c] * wb.y + x2[c] * wc.y + bv.y);
            h1[c][k + 2] = fmaxf(0.f, x0[c] * wa.z + x1[c] * wb.z + x2[c] * wc.z + bv.z);
            h1[c][k + 3] = fmaxf(0.f, x0[c] * wa.w + x1[c] * wb.w + x2[c] * wc.w + bv.w);
        }
    }

    float acc[2];
#pragma unroll
    for (int c = 0; c < 2; ++c) acc[c] = b3v;
#pragma unroll 1
    for (int k = 0; k < 32; k += 4) {
        float4 hb = *(const float4*)(b2d + k);
        float v[2][4];
#pragma unroll
        for (int c = 0; c < 2; ++c) {
            v[c][0] = hb.x; v[c][1] = hb.y; v[c][2] = hb.z; v[c][3] = hb.w;
        }
#pragma unroll
        for (int j = 0; j < 32; ++j) {
            float4 w2v = *(const float4*)(w2d + j * 32 + k);
#pragma unroll
            for (int c = 0; c < 2; ++c) {
                v[c][0] += h1[c][j] * w2v.x;
                v[c][1] += h1[c][j] * w2v.y;
                v[c][2] += h1[c][j] * w2v.z;
                v[c][3] += h1[c][j] * w2v.w;
            }
        }
        float4 w3v = *(const float4*)(w3d + k);
#pragma unroll
        for (int c = 0; c < 2; ++c) {
            acc[c] += fmaxf(0.f, v[c][0]) * w3v.x + fmaxf(0.f, v[c][1]) * w3v.y +
                      fmaxf(0.f, v[c][2]) * w3v.z + fmaxf(0.f, v[c][3]) * w3v.w;
        }
    }
#pragma unroll
    for (int c = 0; c < 2; ++c)
        out[(size_t)(b0 + c * 32) * NG + gg] = acc[c];
}

extern "C" void kernel_launch(void* const* d_in, const int* in_sizes, int n_in,
                              void* d_out, int out_size, void* d_ws, size_t ws_size,
                              hipStream_t stream) {
    const float* data = (const float*)d_in[0];
    const float* A    = (const float*)d_in[1];
    const float* W1   = (const float*)d_in[2];
    const float* b1   = (const float*)d_in[3];
    const float* W2   = (const float*)d_in[4];
    const float* b2   = (const float*)d_in[5];
    const float* W3   = (const float*)d_in[6];
    const float* b3   = (const float*)d_in[7];
    float* out = (float*)d_out;
    float* ws = (float*)d_ws;

    float* D  = ws;
    float* P0 = ws + 524288;    // becomes S
    float* P1 = ws + 1048576;   // becomes M
    float* P2 = ws + 1572864;
    float* P3 = ws + 2097152;
    float* T1 = ws + 2621440;
    float* T2 = ws + 2883584;
    float* gA = ws + 3145728;
    float* gB = ws + 3407872;

    k_D<<<dim3(128), dim3(256), 0, stream>>>(data, D);

    float* gc = gA;
    float* gn = gB;
    for (int it = 0; it < 3; ++it) {
        const float* gin = (it == 0) ? nullptr : gc;
        k_cov<<<dim3(512), dim3(256), 0, stream>>>(A, gin, P0, P1, P2, P3);
        k_invpost<<<dim3(128), dim3(256), 0, stream>>>(P0, P1, P2, P3, D, P0, P1);
        k_feat<<<dim3(1024), dim3(256), 0, stream>>>(A, P0, P1, T1, T2);
        float* dst = (it == 2) ? out : gn;
        k_mlp<<<dim3(512), dim3(256), 0, stream>>>(T1, T2, gin, W1, b1, W2, b2, W3, b3, it, dst);
        float* tmp = gc; gc = gn; gn = tmp;
    }
}

// Round 13
// 499.716 us; speedup vs baseline: 1.0484x; 1.0048x over previous
//
#include <hip/hip_runtime.h>

// Problem constants
#define NB 128      // batch
#define NM 64       // sensors
#define NT 128      // snapshots
#define NG 2048     // gridpoints
#define NH 32       // hidden
// VAR_NOISE = 0.1f

// ---------------------------------------------------------------------------
// Workspace layout (floats):
//  D   [128*64*64]   off 0
//  P0  [128*64*64]   off 524288   (cov partial q0; k_invpost overwrites with S)
//  P1  [128*64*64]   off 1048576  (cov partial q1; k_invpost overwrites with M)
//  P2  [128*64*64]   off 1572864  (cov partial q2)
//  P3  [128*64*64]   off 2097152  (cov partial q3)
//  T1  [128*2048]    off 2621440
//  T2  [128*2048]    off 2883584
//  gA  [128*2048]    off 3145728
//  gB  [128*2048]    off 3407872
// ---------------------------------------------------------------------------

// D[b] = data[b] * data[b]^T / NT    (once per call; data constant)
__global__ __launch_bounds__(256) void k_D(const float* __restrict__ data,
                                           float* __restrict__ D) {
    __shared__ float sd[64 * 133];
    int b = blockIdx.x, t = threadIdx.x;
    const float* db = data + (size_t)b * 8192;
    for (int idx = t; idx < 8192; idx += 256)
        sd[(idx >> 7) * 133 + (idx & 127)] = db[idx];
    __syncthreads();
    int i0 = (t & 15) * 4, j0 = (t >> 4) * 4;
    float acc[4][4];
#pragma unroll
    for (int r = 0; r < 4; ++r)
#pragma unroll
        for (int c = 0; c < 4; ++c) acc[r][c] = 0.f;
    for (int tt = 0; tt < 128; ++tt) {
        float av[4], bv[4];
#pragma unroll
        for (int r = 0; r < 4; ++r) av[r] = sd[(i0 + r) * 133 + tt];
#pragma unroll
        for (int c = 0; c < 4; ++c) bv[c] = sd[(j0 + c) * 133 + tt];
#pragma unroll
        for (int r = 0; r < 4; ++r)
#pragma unroll
            for (int c = 0; c < 4; ++c) acc[r][c] += av[r] * bv[c];
    }
    float* Db = D + (size_t)b * 4096;
#pragma unroll
    for (int r = 0; r < 4; ++r)
#pragma unroll
        for (int c = 0; c < 4; ++c)
            Db[(i0 + r) * 64 + j0 + c] = acc[r][c] * (1.0f / 128.0f);
}

// ---------------------------------------------------------------------------
// k_cov v2 (R8): 8x8 thread tiles, wave-split g-range, LDS tree-merge.
// g == nullptr means gamma = 1 (iteration 0; replaces k_init).
// ---------------------------------------------------------------------------
__global__ __launch_bounds__(256) void k_cov(const float* __restrict__ A,
                                             const float* __restrict__ g,
                                             float* __restrict__ p0,
                                             float* __restrict__ p1,
                                             float* __restrict__ p2,
                                             float* __restrict__ p3) {
    int b = blockIdx.x >> 2, q = blockIdx.x & 3, t = threadIdx.x;
    int goff = q * 512;
    __shared__ float sA[64 * 64];    // [gg][m], one 64-g round
    __shared__ float sAg[64 * 64];   // gamma-scaled copy
    __shared__ float sg[512];
    for (int idx = t; idx < 512; idx += 256)
        sg[idx] = g ? g[(size_t)b * NG + goff + idx] : 1.0f;
    float acc[8][8];
#pragma unroll
    for (int r = 0; r < 8; ++r)
#pragma unroll
        for (int c = 0; c < 8; ++c) acc[r][c] = 0.f;
    int w = t >> 6, l = t & 63;
    int i0 = (l & 7) * 8, j0 = (l >> 3) * 8;
    int m = t >> 2, gs = (t & 3) * 16;   // staging: 4 threads/row, 16 g each

#pragma unroll 1
    for (int rd = 0; rd < 8; ++rd) {
        // issue global loads early; latency overlaps previous round's compute
        const float* Ar = A + (size_t)m * NG + goff + rd * 64 + gs;
        float4 v0 = *(const float4*)Ar;
        float4 v1 = *(const float4*)(Ar + 4);
        float4 v2 = *(const float4*)(Ar + 8);
        float4 v3 = *(const float4*)(Ar + 12);
        __syncthreads();   // previous round's sA/sAg reads complete (rd=0: sg visible)
        {
            const float* sgr = sg + rd * 64 + gs;
            float vv[16] = {v0.x, v0.y, v0.z, v0.w, v1.x, v1.y, v1.z, v1.w,
                            v2.x, v2.y, v2.z, v2.w, v3.x, v3.y, v3.z, v3.w};
#pragma unroll
            for (int u = 0; u < 16; ++u) {
                sA[(gs + u) * 64 + m] = vv[u];
                sAg[(gs + u) * 64 + m] = vv[u] * sgr[u];
            }
        }
        __syncthreads();
        // wave w accumulates its own 16-g slice of this round
#pragma unroll 4
        for (int u = 0; u < 16; ++u) {
            int gg = w * 16 + u;
            const float* avp = sAg + gg * 64 + i0;
            const float* bvp = sA + gg * 64 + j0;
            float4 a0 = *(const float4*)avp;
            float4 a1 = *(const float4*)(avp + 4);
            float4 bb0 = *(const float4*)bvp;
            float4 bb1 = *(const float4*)(bvp + 4);
            float av[8] = {a0.x, a0.y, a0.z, a0.w, a1.x, a1.y, a1.z, a1.w};
            float bv[8] = {bb0.x, bb0.y, bb0.z, bb0.w, bb1.x, bb1.y, bb1.z, bb1.w};
#pragma unroll
            for (int r = 0; r < 8; ++r)
#pragma unroll
                for (int c = 0; c < 8; ++c)
                    acc[r][c] += av[r] * bv[c];
        }
    }

    // ---- merge the 4 wave partials into wave 0 (scalar, lane-consecutive) ----
    __syncthreads();   // all compute reads of sA/sAg done; reuse as merge bufs
    if (w == 1) {
#pragma unroll
        for (int j = 0; j < 64; ++j) sA[j * 64 + l] = acc[j >> 3][j & 7];
    } else if (w == 3) {
#pragma unroll
        for (int j = 0; j < 64; ++j) sAg[j * 64 + l] = acc[j >> 3][j & 7];
    }
    __syncthreads();
    if (w == 0) {
#pragma unroll
        for (int j = 0; j < 64; ++j) acc[j >> 3][j & 7] += sA[j * 64 + l];
    } else if (w == 2) {
#pragma unroll
        for (int j = 0; j < 64; ++j) acc[j >> 3][j & 7] += sAg[j * 64 + l];
    }
    __syncthreads();
    if (w == 2) {
#pragma unroll
        for (int j = 0; j < 64; ++j) sA[j * 64 + l] = acc[j >> 3][j & 7];
    }
    __syncthreads();
    if (w == 0) {
#pragma unroll
        for (int j = 0; j < 64; ++j) acc[j >> 3][j & 7] += sA[j * 64 + l];
        float* dst = (q == 0 ? p0 : q == 1 ? p1 : q == 2 ? p2 : p3) + (size_t)b * 4096;
#pragma unroll
        for (int r = 0; r < 8; ++r) {
            *(float4*)(dst + (i0 + r) * 64 + j0) =
                make_float4(acc[r][0], acc[r][1], acc[r][2], acc[r][3]);
            *(float4*)(dst + (i0 + r) * 64 + j0 + 4) =
                make_float4(acc[r][4], acc[r][5], acc[r][6], acc[r][7]);
        }
    }
}

// ---------------------------------------------------------------------------
// k_invpost v2 (R10: -13us/dispatch): GJ column-split across ALL 4 WAVES.
// R12 note: 512-thread variant analyzed and REJECTED — halving per-thread
// tiles doubles LDS instruction count per CU (reads halve in bytes, not
// instrs); GEMM LDS-issue floor rises 6.1k->9.7k cyc — wash at best.
// ---------------------------------------------------------------------------
#define GJSTEP_MW(RB, WB, KK)                                                 \
    {                                                                         \
        const float* krow = (RB) + (KK) * 68;                                 \
        const float* rowp = (RB) + lane * 68;                                 \
        float4 prow[4], own[4];                                               \
        _Pragma("unroll")                                                     \
        for (int bj = 0; bj < 4; ++bj) prow[bj] = *(const float4*)(krow + cb + 4 * bj); \
        _Pragma("unroll")                                                     \
        for (int bj = 0; bj < 4; ++bj) own[bj] = *(const float4*)(rowp + cb + 4 * bj);  \
        float p = krow[KK];                                                   \
        float c = rowp[KK];                                                   \
        float ps = (__builtin_fabsf(p) < 1e-12f) ? (p >= 0.f ? 1e-12f : -1e-12f) : p; \
        float pinv = __builtin_amdgcn_rcpf(ps);                               \
        bool isk = (lane == (KK));                                            \
        float n  = isk ? 0.0f : 1.0f;                                         \
        float m2 = isk ? -pinv : c * pinv;                                    \
        float* wr = (WB) + lane * 68;                                         \
        _Pragma("unroll")                                                     \
        for (int bj = 0; bj < 4; ++bj) {                                      \
            float4 res;                                                       \
            res.x = own[bj].x * n - m2 * prow[bj].x;                          \
            res.y = own[bj].y * n - m2 * prow[bj].y;                          \
            res.z = own[bj].z * n - m2 * prow[bj].z;                          \
            res.w = own[bj].w * n - m2 * prow[bj].w;                          \
            *(float4*)(wr + cb + 4 * bj) = res;                               \
        }                                                                     \
        if (((KK) >> 4) == wv)                                                \
            wr[KK] = isk ? pinv : -m2;   /* column-k fix, owning wave only */ \
    }

#define GEMMT(Ash, Bsh)                                                       \
    {                                                                         \
        _Pragma("unroll")                                                     \
        for (int rr = 0; rr < 4; ++rr)                                        \
            for (int cc = 0; cc < 4; ++cc) acc[rr][cc] = 0.f;                 \
        _Pragma("unroll 4")                                                   \
        for (int kk = 0; kk < 64; kk += 4) {                                  \
            float4 av[4], bv[4];                                              \
            _Pragma("unroll")                                                 \
            for (int qq = 0; qq < 4; ++qq) {                                  \
                av[qq] = *(const float4*)((Ash) + (kk + qq) * 68 + i0);       \
                bv[qq] = *(const float4*)((Bsh) + (kk + qq) * 68 + j0);       \
            }                                                                 \
            _Pragma("unroll")                                                 \
            for (int qq = 0; qq < 4; ++qq) {                                  \
                acc[0][0] += av[qq].x * bv[qq].x; acc[0][1] += av[qq].x * bv[qq].y; \
                acc[0][2] += av[qq].x * bv[qq].z; acc[0][3] += av[qq].x * bv[qq].w; \
                acc[1][0] += av[qq].y * bv[qq].x; acc[1][1] += av[qq].y * bv[qq].y; \
                acc[1][2] += av[qq].y * bv[qq].z; acc[1][3] += av[qq].y * bv[qq].w; \
                acc[2][0] += av[qq].z * bv[qq].x; acc[2][1] += av[qq].z * bv[qq].y; \
                acc[2][2] += av[qq].z * bv[qq].z; acc[2][3] += av[qq].z * bv[qq].w; \
                acc[3][0] += av[qq].w * bv[qq].x; acc[3][1] += av[qq].w * bv[qq].y; \
                acc[3][2] += av[qq].w * bv[qq].z; acc[3][3] += av[qq].w * bv[qq].w; \
            }                                                                 \
        }                                                                     \
    }

__global__ __launch_bounds__(256, 1) void k_invpost(const float* p0, const float* p1,
                                                    const float* p2, const float* p3,
                                                    const float* Dws,
                                                    float* Sbuf, float* Mbuf) {
    __shared__ float sX[64 * 68];   // GJ ping-pong even / final X / later D
    __shared__ float sA[64 * 68];   // Sigma copy -> X2
    __shared__ float sR[64 * 68];   // GJ ping-pong odd / R -> P
    int t = threadIdx.x, b = blockIdx.x;
    size_t boff = (size_t)b * 4096;

    // D into registers (latency hidden behind GJ phase)
    float4 dreg[4];
#pragma unroll
    for (int u = 0; u < 4; ++u)
        dreg[u] = ((const float4*)(Dws + boff))[u * 256 + t];

    // stage Sigma = p0+p1+p2+p3 + 0.1 I into sX and sA
#pragma unroll
    for (int u = 0; u < 4; ++u) {
        int idx = u * 1024 + t * 4;
        int i = idx >> 6, j = idx & 63;
        float4 v0 = *(const float4*)(p0 + boff + idx);
        float4 v1 = *(const float4*)(p1 + boff + idx);
        float4 v2 = *(const float4*)(p2 + boff + idx);
        float4 v3 = *(const float4*)(p3 + boff + idx);
        float4 v = make_float4((v0.x + v1.x) + (v2.x + v3.x),
                               (v0.y + v1.y) + (v2.y + v3.y),
                               (v0.z + v1.z) + (v2.z + v3.z),
                               (v0.w + v1.w) + (v2.w + v3.w));
        int d = i - j;
        if (d >= 0 && d < 4) (&v.x)[d] += 0.1f;
        *(float4*)(sX + i * 68 + j) = v;
        *(float4*)(sA + i * 68 + j) = v;
    }
    __syncthreads();

    // ---- Gauss-Jordan, all 4 waves (column-split), barrier per step ----
    {
        int lane = t & 63, wv = t >> 6, cb = wv * 16;
#pragma unroll 1
        for (int k2 = 0; k2 < 32; ++k2) {
            GJSTEP_MW(sX, sR, 2 * k2);        // even step: sX -> sR
            __syncthreads();
            GJSTEP_MW(sR, sX, 2 * k2 + 1);    // odd step:  sR -> sX
            __syncthreads();
        }
    }

    int i0 = (t & 15) * 4, j0 = (t >> 4) * 4;
    float acc[4][4];

    // GEMM1: R = 2I - Sigma*X   (A = sA = Sigma, symmetric -> transposed read)
    GEMMT(sA, sX);
#pragma unroll
    for (int rr = 0; rr < 4; ++rr)
#pragma unroll
        for (int cc = 0; cc < 4; ++cc)
            sR[(i0 + rr) * 68 + j0 + cc] =
                ((i0 + rr) == (j0 + cc) ? 2.0f : 0.0f) - acc[rr][cc];
    __syncthreads();

    // GEMM2: X2 = X*R  (X symmetric)  -> Sbuf global + sA (Sigma dead)
    GEMMT(sX, sR);
#pragma unroll
    for (int rr = 0; rr < 4; ++rr) {
#pragma unroll
        for (int cc = 0; cc < 4; ++cc)
            sA[(i0 + rr) * 68 + j0 + cc] = acc[rr][cc];
        *(float4*)(Sbuf + boff + (i0 + rr) * 64 + j0) =
            make_float4(acc[rr][0], acc[rr][1], acc[rr][2], acc[rr][3]);
    }
    __syncthreads();

    // scatter D into sX (X dead)
#pragma unroll
    for (int u = 0; u < 4; ++u) {
        int idx = u * 1024 + t * 4;
        *(float4*)(sX + (idx >> 6) * 68 + (idx & 63)) = dreg[u];
    }
    __syncthreads();

    // GEMM3: P = D*X2  (D symmetric) -> sR (R dead)
    GEMMT(sX, sA);
    __syncthreads();
#pragma unroll
    for (int rr = 0; rr < 4; ++rr)
#pragma unroll
        for (int cc = 0; cc < 4; ++cc)
            sR[(i0 + rr) * 68 + j0 + cc] = acc[rr][cc];
    __syncthreads();

    // GEMM4: M = X2*P  (X2 symmetric) -> Mbuf
    GEMMT(sA, sR);
#pragma unroll
    for (int rr = 0; rr < 4; ++rr)
        *(float4*)(Mbuf + boff + (i0 + rr) * 64 + j0) =
            make_float4(acc[rr][0], acc[rr][1], acc[rr][2], acc[rr][3]);
}

// ---------------------------------------------------------------------------
// k_feat v7 (closed at ~58-61us; 53% VALUBusy is structure-intrinsic).
// ---------------------------------------------------------------------------
__global__ __launch_bounds__(256, 1) void k_feat(const float* __restrict__ A,
                                                 const float* __restrict__ Sbuf,
                                                 const float* __restrict__ Mbuf,
                                                 float* __restrict__ T1,
                                                 float* __restrict__ T2) {
    __shared__ float sS[4096];
    __shared__ float sM[4096];
    __shared__ float sa[4096];     // A-tile phase buffer: [16 k][256 g]
    int t = threadIdx.x;
    int b = blockIdx.x >> 3, tile = blockIdx.x & 7;
    const float* Abase = A + tile * 256;
    {
        const float4* S4 = (const float4*)(Sbuf + (size_t)b * 4096);
        const float4* M4 = (const float4*)(Mbuf + (size_t)b * 4096);
#pragma unroll
        for (int u = 0; u < 4; ++u) {
            ((float4*)sS)[u * 256 + t] = S4[u * 256 + t];
            ((float4*)sM)[u * 256 + t] = M4[u * 256 + t];
        }
        // stage A phase 0 (k = 0..15)
#pragma unroll
        for (int u = 0; u < 4; ++u) {
            int idx = u * 1024 + t * 4;
            int kk = idx >> 8, gl = idx & 255;
            *(float4*)(sa + idx) = *(const float4*)(Abase + (size_t)kk * NG + gl);
        }
    }
    int iq = t >> 4, gq = t & 15;
    int i0 = iq * 4;
    float accS[4][16], accM[4][16];
#pragma unroll
    for (int r = 0; r < 4; ++r)
#pragma unroll
        for (int c = 0; c < 16; ++c) { accS[r][c] = 0.f; accM[r][c] = 0.f; }
    __syncthreads();

#pragma unroll 1
    for (int p = 0; p < 4; ++p) {
        if (p) {
            __syncthreads();   // previous phase's sa reads complete
#pragma unroll
            for (int u = 0; u < 4; ++u) {
                int idx = u * 1024 + t * 4;
                int kk = idx >> 8, gl = idx & 255;
                *(float4*)(sa + idx) =
                    *(const float4*)(Abase + (size_t)(p * 16 + kk) * NG + gl);
            }
            __syncthreads();
        }
#pragma unroll 2
        for (int kk = 0; kk < 16; ++kk) {
            int k = p * 16 + kk;
            float4 sf = *(const float4*)(sS + k * 64 + i0);   // S[i0..3][k]
            float4 mf = *(const float4*)(sM + k * 64 + i0);   // M[i0..3][k]
            const float* ak = sa + kk * 256 + gq * 4;
            float4 a0 = *(const float4*)(ak);
            float4 a1 = *(const float4*)(ak + 64);
            float4 a2 = *(const float4*)(ak + 128);
            float4 a3 = *(const float4*)(ak + 192);
            float af[16] = {a0.x, a0.y, a0.z, a0.w, a1.x, a1.y, a1.z, a1.w,
                            a2.x, a2.y, a2.z, a2.w, a3.x, a3.y, a3.z, a3.w};
#pragma unroll
            for (int r = 0; r < 4; ++r) {
                float sr = (&sf.x)[r];
                float mr = (&mf.x)[r];
#pragma unroll
                for (int c = 0; c < 16; ++c) {
                    accS[r][c] += sr * af[c];
                    accM[r][c] += mr * af[c];
                }
            }
        }
    }

    // epilogue: multiply by own A rows (global, one-shot, L1-hot)
    float pS[16], pM[16];
#pragma unroll
    for (int c = 0; c < 16; ++c) { pS[c] = 0.f; pM[c] = 0.f; }
#pragma unroll
    for (int r = 0; r < 4; ++r) {
        const float* arp = A + (size_t)(i0 + r) * NG + tile * 256 + gq * 4;
        float4 b0 = *(const float4*)(arp);
        float4 b1 = *(const float4*)(arp + 64);
        float4 b2 = *(const float4*)(arp + 128);
        float4 b3 = *(const float4*)(arp + 192);
        float ar[16] = {b0.x, b0.y, b0.z, b0.w, b1.x, b1.y, b1.z, b1.w,
                        b2.x, b2.y, b2.z, b2.w, b3.x, b3.y, b3.z, b3.w};
#pragma unroll
        for (int c = 0; c < 16; ++c) {
            pS[c] += ar[c] * accS[r][c];
            pM[c] += ar[c] * accM[r][c];
        }
    }
    __syncthreads();   // k-loop reads of sS/sM done; reuse as scratch

    // scratch: sS[iq][g_local] S-partials, sM likewise (16 x 256)
#pragma unroll
    for (int ch = 0; ch < 4; ++ch) {
        *(float4*)(sS + iq * 256 + ch * 64 + gq * 4) =
            make_float4(pS[ch * 4], pS[ch * 4 + 1], pS[ch * 4 + 2], pS[ch * 4 + 3]);
        *(float4*)(sM + iq * 256 + ch * 64 + gq * 4) =
            make_float4(pM[ch * 4], pM[ch * 4 + 1], pM[ch * 4 + 2], pM[ch * 4 + 3]);
    }
    __syncthreads();

    // final 16-way reduce: thread t owns g_local = t (lanes consecutive: no conflict)
    float sumS = 0.f, sumM = 0.f;
#pragma unroll
    for (int q = 0; q < 16; ++q) {
        sumS += sS[q * 256 + t];
        sumM += sM[q * 256 + t];
    }
    size_t base = (size_t)b * NG + tile * 256 + t;
    T2[base] = fabsf(sumS);
    T1[base] = sumM;
}

// ---------------------------------------------------------------------------
// k_mlp v5: 4-way batch split. R12: v4 (2-way) gained -6.3us/dispatch —
// direction confirmed (latency-bound), magnitude short: still exposed at
// 2 waves/SIMD. v5: grid 1024, quarter = bid&3 selects 32 batch points
// (1/thread); LDS 39.6KB x 4 = 158.3KB < 160 -> 4 blocks/CU = 4 waves/
// SIMD. h1[32], VGPR ~70. Staging duplicated 4x (40MB/dispatch, L3-hot,
// ~6us aggregate) — acceptable vs latency recovery.
// Decision rule: dtotal >= 10us -> TLP confirmed; < 10us -> k_mlp closed,
// declare roofline next round. gcur == nullptr means gamma = 1.
// ---------------------------------------------------------------------------
__global__ __launch_bounds__(256, 1) void k_mlp(const float* __restrict__ T1,
                                                const float* __restrict__ T2,
                                                const float* __restrict__ gcur,
                                                const float* __restrict__ W1,
                                                const float* __restrict__ b1,
                                                const float* __restrict__ W2,
                                                const float* __restrict__ b2,
                                                const float* __restrict__ W3,
                                                const float* __restrict__ b3,
                                                int it, float* __restrict__ out) {
    // LDS regions (floats): W1 [0,800) stride 100 | b1 [800,1088) stride 36
    // | W2 [1088,9312) stride 1028 | b2 [9312,9600) stride 36
    // | W3 [9600,9888) stride 36 | b3 [9888,9896)
    __shared__ float w[9896];
    int t = threadIdx.x;
    int gb = blockIdx.x >> 2, quarter = blockIdx.x & 3;
    int g0 = gb * 8;
    {
        size_t gbase = (size_t)it * NG + g0;
        const float* srcW1 = W1 + gbase * 96;
        const float* srcB1 = b1 + gbase * 32;
        const float* srcW2 = W2 + gbase * 1024;
        const float* srcB2 = b2 + gbase * 32;
        const float* srcW3 = W3 + gbase * 32;
        const float* srcB3 = b3 + gbase;
#pragma unroll
        for (int u = 0; u < 8; ++u)   // W2: one gl per u (2048 f4 / 8)
            *(float4*)(w + 1088 + u * 1028 + t * 4) =
                ((const float4*)srcW2)[u * 256 + t];
        if (t < 192) {                // W1: 192 f4 = 8 gl x 24 f4
            int gl = t / 24, j4 = t % 24;
            *(float4*)(w + gl * 100 + j4 * 4) = ((const float4*)srcW1)[t];
        } else {                      // b1: 64 f4 = 8 gl x 8 f4
            int i = t - 192, gl = i >> 3, j4 = i & 7;
            *(float4*)(w + 800 + gl * 36 + j4 * 4) = ((const float4*)srcB1)[i];
        }
        if (t < 64) {                 // b2
            int gl = t >> 3, j4 = t & 7;
            *(float4*)(w + 9312 + gl * 36 + j4 * 4) = ((const float4*)srcB2)[t];
        } else if (t < 128) {         // W3
            int i = t - 64, gl = i >> 3, j4 = i & 7;
            *(float4*)(w + 9600 + gl * 36 + j4 * 4) = ((const float4*)srcW3)[i];
        } else if (t < 136) {         // b3: 8 scalars
            w[9888 + (t - 128)] = srcB3[t - 128];
        }
    }
    __syncthreads();
    int gl = t & 7, gg = g0 + gl;
    const float* w1d = w + gl * 100;
    const float* b1d = w + 800 + gl * 36;
    const float* w2d = w + 1088 + gl * 1028;
    const float* b2d = w + 9312 + gl * 36;
    const float* w3d = w + 9600 + gl * 36;
    float b3v = w[9888 + gl];
    int b0 = (t >> 3) + quarter * 32;   // one batch point per thread

    float x0, x1, x2;
    {
        size_t xo = (size_t)b0 * NG + gg;
        x0 = T1[xo]; x1 = T2[xo];
        x2 = gcur ? gcur[xo] : 1.0f;
    }

    float h1[32];
#pragma unroll
    for (int k = 0; k < 32; k += 4) {
        float4 wa = *(const float4*)(w1d + k);
        float4 wb = *(const float4*)(w1d + 32 + k);
        float4 wc = *(const float4*)(w1d + 64 + k);
        float4 bv = *(const float4*)(b1d + k);
        h1[k + 0] = fmaxf(0.f, x0 * wa.x + x1 * wb.x + x2 * wc.x + bv.x);
        h1[k + 1] = fmaxf(0.f, x0 * wa.y + x1 * wb.y + x2 * wc.y + bv.y);
        h1[k + 2] = fmaxf(0.f, x0 * wa.z + x1 * wb.z + x2 * wc.z + bv.z);
        h1[k + 3] = fmaxf(0.f, x0 * wa.w + x1 * wb.w + x2 * wc.w + bv.w);
    }

    float acc = b3v;
#pragma unroll 1
    for (int k = 0; k < 32; k += 4) {
        float4 hb = *(const float4*)(b2d + k);
        float v0 = hb.x, v1 = hb.y, v2 = hb.z, v3 = hb.w;
#pragma unroll
        for (int j = 0; j < 32; ++j) {
            float4 w2v = *(const float4*)(w2d + j * 32 + k);
            v0 += h1[j] * w2v.x;
            v1 += h1[j] * w2v.y;
            v2 += h1[j] * w2v.z;
            v3 += h1[j] * w2v.w;
        }
        float4 w3v = *(const float4*)(w3d + k);
        acc += fmaxf(0.f, v0) * w3v.x + fmaxf(0.f, v1) * w3v.y +
               fmaxf(0.f, v2) * w3v.z + fmaxf(0.f, v3) * w3v.w;
    }
    out[(size_t)b0 * NG + gg] = acc;
}

extern "C" void kernel_launch(void* const* d_in, const int* in_sizes, int n_in,
                              void* d_out, int out_size, void* d_ws, size_t ws_size,
                              hipStream_t stream) {
    const float* data = (const float*)d_in[0];
    const float* A    = (const float*)d_in[1];
    const float* W1   = (const float*)d_in[2];
    const float* b1   = (const float*)d_in[3];
    const float* W2   = (const float*)d_in[4];
    const float* b2   = (const float*)d_in[5];
    const float* W3   = (const float*)d_in[6];
    const float* b3   = (const float*)d_in[7];
    float* out = (float*)d_out;
    float* ws = (float*)d_ws;

    float* D  = ws;
    float* P0 = ws + 524288;    // becomes S
    float* P1 = ws + 1048576;   // becomes M
    float* P2 = ws + 1572864;
    float* P3 = ws + 2097152;
    float* T1 = ws + 2621440;
    float* T2 = ws + 2883584;
    float* gA = ws + 3145728;
    float* gB = ws + 3407872;

    k_D<<<dim3(128), dim3(256), 0, stream>>>(data, D);

    float* gc = gA;
    float* gn = gB;
    for (int it = 0; it < 3; ++it) {
        const float* gin = (it == 0) ? nullptr : gc;
        k_cov<<<dim3(512), dim3(256), 0, stream>>>(A, gin, P0, P1, P2, P3);
        k_invpost<<<dim3(128), dim3(256), 0, stream>>>(P0, P1, P2, P3, D, P0, P1);
        k_feat<<<dim3(1024), dim3(256), 0, stream>>>(A, P0, P1, T1, T2);
        float* dst = (it == 2) ? out : gn;
        k_mlp<<<dim3(1024), dim3(256), 0, stream>>>(T1, T2, gin, W1, b1, W2, b2, W3, b3, it, dst);
        float* tmp = gc; gc = gn; gn = tmp;
    }
}